// Round 10
// baseline (3974.171 us; speedup 1.0000x reference)
//
#include <hip/hip_runtime.h>

#define N_ROWS 16384
#define D_DIM  2048
#define BM 128
#define BN 128
#define BK 32
#define NKT (D_DIM / BK)   // 64 K-steps

typedef __attribute__((ext_vector_type(8)))  _Float16 half8;
typedef __attribute__((ext_vector_type(4)))  _Float16 half4_t;
typedef __attribute__((ext_vector_type(4)))  float floatx4;

typedef __attribute__((address_space(1))) const unsigned int as1_uint;
typedef __attribute__((address_space(3))) unsigned int as3_uint;

__device__ __forceinline__ void gload_lds16(const _Float16* g, _Float16* l) {
    __builtin_amdgcn_global_load_lds((as1_uint*)g, (as3_uint*)l, 16, 0, 0);
}

// ---------------------------------------------------------------------------
// Combined pre-pass: one dispatch splits BOTH X (with mask bits) and A.
//   hi = (half)x ; lo = (half)((x - hi) * 4096)
// ---------------------------------------------------------------------------
__global__ void split_all_kernel(const float4* __restrict__ Xs,
                                 half4_t* __restrict__ Xdh,
                                 half4_t* __restrict__ Xdl,
                                 unsigned char* __restrict__ mask,
                                 const float4* __restrict__ As,
                                 half4_t* __restrict__ Adh,
                                 half4_t* __restrict__ Adl,
                                 int nX8, int total8)
{
    int i = blockIdx.x * blockDim.x + threadIdx.x;
    if (i >= total8) return;

    const float4* src; half4_t* dh; half4_t* dl; int j; bool domask;
    if (i < nX8) { src = Xs; dh = Xdh; dl = Xdl; j = i;       domask = true;  }
    else         { src = As; dh = Adh; dl = Adl; j = i - nX8; domask = false; }

    float4 a = src[2 * j];
    float4 b = src[2 * j + 1];
    half4_t ha, la, hb, lb;
    ha[0] = (_Float16)a.x; ha[1] = (_Float16)a.y;
    ha[2] = (_Float16)a.z; ha[3] = (_Float16)a.w;
    la[0] = (_Float16)((a.x - (float)ha[0]) * 4096.0f);
    la[1] = (_Float16)((a.y - (float)ha[1]) * 4096.0f);
    la[2] = (_Float16)((a.z - (float)ha[2]) * 4096.0f);
    la[3] = (_Float16)((a.w - (float)ha[3]) * 4096.0f);
    hb[0] = (_Float16)b.x; hb[1] = (_Float16)b.y;
    hb[2] = (_Float16)b.z; hb[3] = (_Float16)b.w;
    lb[0] = (_Float16)((b.x - (float)hb[0]) * 4096.0f);
    lb[1] = (_Float16)((b.y - (float)hb[1]) * 4096.0f);
    lb[2] = (_Float16)((b.z - (float)hb[2]) * 4096.0f);
    lb[3] = (_Float16)((b.w - (float)hb[3]) * 4096.0f);
    dh[2 * j] = ha; dh[2 * j + 1] = hb;
    dl[2 * j] = la; dl[2 * j + 1] = lb;
    if (domask) {
        unsigned int m = 0;
        m |= (a.x != 0.0f) ? 0x01u : 0u;  m |= (a.y != 0.0f) ? 0x02u : 0u;
        m |= (a.z != 0.0f) ? 0x04u : 0u;  m |= (a.w != 0.0f) ? 0x08u : 0u;
        m |= (b.x != 0.0f) ? 0x10u : 0u;  m |= (b.y != 0.0f) ? 0x20u : 0u;
        m |= (b.z != 0.0f) ? 0x40u : 0u;  m |= (b.w != 0.0f) ? 0x80u : 0u;
        mask[j] = (unsigned char)m;
    }
}

// ---------------------------------------------------------------------------
// GEMM (16x16x32 f16 MFMA) on pre-split fp16.
//   dot = hi*hi + (hi*lo + lo*hi)/4096   [fp32-level accuracy]
// SINGLE-buffer variant of the proven round-3/7/9 hot loop: LDS 32 KiB
// (4 arrays x 8 KiB) -> 4 blocks/CU (16 waves) instead of 2. Two barriers
// per K-step; the vmcnt(0) drain at the first barrier hides behind the
// other 3 resident blocks' compute (cross-block TLP replaces the dbuf ILP).
// Staging map, XOR slot swizzle, fragment reads, epilogue: byte-identical.
// ---------------------------------------------------------------------------
__global__ __launch_bounds__(256, 4)
void gemm_presplit_kernel(const _Float16* __restrict__ Xh,
                          const _Float16* __restrict__ Xl,
                          const _Float16* __restrict__ Ah,
                          const _Float16* __restrict__ Al,
                          const unsigned char* __restrict__ maskbits,
                          const float* __restrict__ bias,
                          float* __restrict__ out,
                          float* __restrict__ partials)
{
    __shared__ __align__(16) _Float16 sXh[BM * BK];
    __shared__ __align__(16) _Float16 sXl[BM * BK];
    __shared__ __align__(16) _Float16 sAh[BN * BK];
    __shared__ __align__(16) _Float16 sAl[BN * BK];

    const int t   = threadIdx.x;
    const int bid = blockIdx.x;

    // Round-3 XCD-chunked swizzle: r_tile fastest within an XCD.
    const int xcd    = bid & 7;
    const int local  = bid >> 3;          // 0..255
    const int r_tile = (xcd << 4) + (local & 15);
    const int c_tile = local >> 4;
    const int m0 = r_tile * BM;
    const int n0 = c_tile * BN;

    const int lane  = t & 63;
    const int w     = t >> 6;
    const int wr    = w >> 1;
    const int wc    = w & 1;
    const int lrow  = lane & 15;
    const int lslot = lane >> 4;

    floatx4 acc1[4][4], acc2[4][4];
    #pragma unroll
    for (int mi = 0; mi < 4; ++mi)
        #pragma unroll
        for (int ni = 0; ni < 4; ++ni)
            #pragma unroll
            for (int j = 0; j < 4; ++j) { acc1[mi][ni][j] = 0.f; acc2[mi][ni][j] = 0.f; }

    // Per-wave staging region (8 x 1KB global_load_lds per K-step).
    const _Float16* gsrc;
    _Float16* lb;
    if      (w == 0) { gsrc = Xh + (size_t)m0 * D_DIM; lb = &sXh[0]; }
    else if (w == 1) { gsrc = Xl + (size_t)m0 * D_DIM; lb = &sXl[0]; }
    else if (w == 2) { gsrc = Ah + (size_t)n0 * D_DIM; lb = &sAh[0]; }
    else             { gsrc = Al + (size_t)n0 * D_DIM; lb = &sAl[0]; }

    // Pre-swizzled per-lane global offsets (halves), one per instruction i.
    // (4 consecutive lanes cover one row's 64B -> full coalescing.)
    int off8[8];
    #pragma unroll
    for (int i = 0; i < 8; ++i) {
        int c = i * 64 + lane;            // linear 16B chunk index in LDS
        int row = c >> 2;                 // 4 chunks per row
        int sp  = c & 3;                  // stored slot
        int kslot = sp ^ ((row >> 1) & 3);
        off8[i] = row * D_DIM + kslot * 8;
    }

    auto issue = [&](int kt) {
        const _Float16* gk = gsrc + kt * BK;
        #pragma unroll
        for (int i = 0; i < 8; ++i)
            gload_lds16(gk + off8[i], lb + i * 512);
    };

    issue(0);

    for (int kt = 0; kt < NKT; ++kt) {
        __syncthreads();                  // drains this wave's loads; all landed

        half8 bhf[4], blf[4];
        #pragma unroll
        for (int ni = 0; ni < 4; ++ni) {
            int row = wc * 64 + ni * 16 + lrow;
            int off = row * BK + ((lslot ^ ((row >> 1) & 3)) << 3);
            bhf[ni] = *reinterpret_cast<const half8*>(&sAh[off]);
            blf[ni] = *reinterpret_cast<const half8*>(&sAl[off]);
        }
        #pragma unroll
        for (int mi = 0; mi < 4; ++mi) {
            int row = wr * 64 + mi * 16 + lrow;
            int off = row * BK + ((lslot ^ ((row >> 1) & 3)) << 3);
            half8 ah = *reinterpret_cast<const half8*>(&sXh[off]);
            half8 al = *reinterpret_cast<const half8*>(&sXl[off]);
            #pragma unroll
            for (int ni = 0; ni < 4; ++ni) {
                acc1[mi][ni] = __builtin_amdgcn_mfma_f32_16x16x32_f16(ah, bhf[ni], acc1[mi][ni], 0, 0, 0);
                acc2[mi][ni] = __builtin_amdgcn_mfma_f32_16x16x32_f16(ah, blf[ni], acc2[mi][ni], 0, 0, 0);
                acc2[mi][ni] = __builtin_amdgcn_mfma_f32_16x16x32_f16(al, bhf[ni], acc2[mi][ni], 0, 0, 0);
            }
        }

        if (kt + 1 < NKT) {
            __syncthreads();              // all waves done reading LDS
            issue(kt + 1);                // safe to overwrite the buffer
        }
    }

    // Epilogue: bias + mask (bit array), write masked y_pred, fused per-row
    // partial sums. C/D layout: col = lane&15, row = (lane>>4)*4 + j.
    #pragma unroll
    for (int mi = 0; mi < 4; ++mi) {
        float rs[4];
        #pragma unroll
        for (int j = 0; j < 4; ++j) rs[j] = 0.f;
        #pragma unroll
        for (int ni = 0; ni < 4; ++ni) {
            int c = n0 + wc * 64 + ni * 16 + lrow;
            float bv = bias[c];
            #pragma unroll
            for (int j = 0; j < 4; ++j) {
                int r = m0 + wr * 64 + mi * 16 + lslot * 4 + j;
                size_t idx = (size_t)r * D_DIM + c;
                float v = acc1[mi][ni][j] + acc2[mi][ni][j] * (1.0f / 4096.0f) + bv;
                unsigned int bit = (maskbits[idx >> 3] >> (c & 7)) & 1u;
                float mv = bit ? v : 0.0f;
                out[idx] = mv;
                rs[j] += mv;
            }
        }
        #pragma unroll
        for (int j = 0; j < 4; ++j) {
            float s = rs[j];
            s += __shfl_xor(s, 1, 64);
            s += __shfl_xor(s, 2, 64);
            s += __shfl_xor(s, 4, 64);
            s += __shfl_xor(s, 8, 64);
            if (lrow == 0) {
                int r = m0 + wr * 64 + mi * 16 + lslot * 4 + j;
                partials[(size_t)r * 32 + c_tile * 2 + wc] = s;
            }
        }
    }
}

// ---------------------------------------------------------------------------
// Fused: reduce 32 partials per row -> inv, then scale the row in-place.
// ---------------------------------------------------------------------------
__global__ void scale_fused_kernel(float* __restrict__ out,
                                   const float* __restrict__ partials)
{
    int r   = blockIdx.x * 8 + (threadIdx.x >> 5);
    int l32 = threadIdx.x & 31;
    float s = partials[(size_t)r * 32 + l32];
    s += __shfl_xor(s, 1, 32);
    s += __shfl_xor(s, 2, 32);
    s += __shfl_xor(s, 4, 32);
    s += __shfl_xor(s, 8, 32);
    s += __shfl_xor(s, 16, 32);
    float inv = (s != 0.0f) ? (1.0f / s) : 0.0f;
    float4* rowp = reinterpret_cast<float4*>(out + (size_t)r * D_DIM);
    #pragma unroll
    for (int j = 0; j < 16; ++j) {
        float4 v = rowp[j * 32 + l32];
        v.x *= inv; v.y *= inv; v.z *= inv; v.w *= inv;
        rowp[j * 32 + l32] = v;
    }
}

// ---------------------------------------------------------------------------
// Fallback GEMM (round-1 proven kernel) if ws_size is too small.
// ---------------------------------------------------------------------------
__global__ __launch_bounds__(256, 2)
void gemm_mask_kernel(const float* __restrict__ X,
                      const float* __restrict__ A,
                      const float* __restrict__ bias,
                      float* __restrict__ out)
{
    __shared__ __align__(16) _Float16 sXh[2][BM * BK];
    __shared__ __align__(16) _Float16 sXl[2][BM * BK];
    __shared__ __align__(16) _Float16 sAh[2][BN * BK];
    __shared__ __align__(16) _Float16 sAl[2][BN * BK];

    const int t   = threadIdx.x;
    const int bid = blockIdx.x;
    const int xcd    = bid & 7;
    const int local  = bid >> 3;
    const int r_tile = (xcd << 4) + (local & 15);
    const int c_tile = local >> 4;
    const int m0 = r_tile * BM;
    const int n0 = c_tile * BN;

    const int lane  = t & 63;
    const int w     = t >> 6;
    const int wr    = w >> 1;
    const int wc    = w & 1;
    const int lrow  = lane & 15;
    const int lslot = lane >> 4;

    const float4* X4 = reinterpret_cast<const float4*>(X);
    const float4* A4 = reinterpret_cast<const float4*>(A);

    floatx4 acc1[4][4], acc2[4][4];
    #pragma unroll
    for (int mi = 0; mi < 4; ++mi)
        #pragma unroll
        for (int ni = 0; ni < 4; ++ni)
            #pragma unroll
            for (int j = 0; j < 4; ++j) { acc1[mi][ni][j] = 0.f; acc2[mi][ni][j] = 0.f; }

    float4 rx[4], ra[4];
    #pragma unroll
    for (int i = 0; i < 4; ++i) {
        int f = i * 256 + t; int row = f >> 3; int k4 = f & 7;
        rx[i] = X4[(size_t)(m0 + row) * (D_DIM / 4) + k4];
        ra[i] = A4[(size_t)(n0 + row) * (D_DIM / 4) + k4];
    }

    auto stage = [&](const float4* rv, _Float16* dsh, _Float16* dsl) {
        #pragma unroll
        for (int i = 0; i < 4; ++i) {
            int f = i * 256 + t; int row = f >> 3; int k4 = f & 7;
            float4 v = rv[i];
            half4_t h, l;
            h[0] = (_Float16)v.x; h[1] = (_Float16)v.y;
            h[2] = (_Float16)v.z; h[3] = (_Float16)v.w;
            l[0] = (_Float16)((v.x - (float)h[0]) * 4096.0f);
            l[1] = (_Float16)((v.y - (float)h[1]) * 4096.0f);
            l[2] = (_Float16)((v.z - (float)h[2]) * 4096.0f);
            l[3] = (_Float16)((v.w - (float)h[3]) * 4096.0f);
            int off = row * BK + ((((k4 >> 1) ^ ((row >> 1) & 3)) << 3) + ((k4 & 1) << 2));
            *reinterpret_cast<half4_t*>(dsh + off) = h;
            *reinterpret_cast<half4_t*>(dsl + off) = l;
        }
    };

    stage(rx, &sXh[0][0], &sXl[0][0]);
    stage(ra, &sAh[0][0], &sAl[0][0]);

    int cur = 0;
    for (int kt = 0; kt < NKT; ++kt) {
        __syncthreads();
        const bool more = (kt + 1 < NKT);
        if (more) {
            int kb = (kt + 1) * (BK / 4);
            #pragma unroll
            for (int i = 0; i < 4; ++i) {
                int f = i * 256 + t; int row = f >> 3; int k4 = f & 7;
                rx[i] = X4[(size_t)(m0 + row) * (D_DIM / 4) + kb + k4];
                ra[i] = A4[(size_t)(n0 + row) * (D_DIM / 4) + kb + k4];
            }
        }

        half8 bhf[4], blf[4];
        #pragma unroll
        for (int ni = 0; ni < 4; ++ni) {
            int row = wc * 64 + ni * 16 + lrow;
            int off = row * BK + ((lslot ^ ((row >> 1) & 3)) << 3);
            bhf[ni] = *reinterpret_cast<const half8*>(&sAh[cur][off]);
            blf[ni] = *reinterpret_cast<const half8*>(&sAl[cur][off]);
        }
        #pragma unroll
        for (int mi = 0; mi < 4; ++mi) {
            int row = wr * 64 + mi * 16 + lrow;
            int off = row * BK + ((lslot ^ ((row >> 1) & 3)) << 3);
            half8 ah = *reinterpret_cast<const half8*>(&sXh[cur][off]);
            half8 al = *reinterpret_cast<const half8*>(&sXl[cur][off]);
            #pragma unroll
            for (int ni = 0; ni < 4; ++ni) {
                acc1[mi][ni] = __builtin_amdgcn_mfma_f32_16x16x32_f16(ah, bhf[ni], acc1[mi][ni], 0, 0, 0);
                acc2[mi][ni] = __builtin_amdgcn_mfma_f32_16x16x32_f16(ah, blf[ni], acc2[mi][ni], 0, 0, 0);
                acc2[mi][ni] = __builtin_amdgcn_mfma_f32_16x16x32_f16(al, bhf[ni], acc2[mi][ni], 0, 0, 0);
            }
        }

        if (more) {
            int nxt = cur ^ 1;
            stage(rx, &sXh[nxt][0], &sXl[nxt][0]);
            stage(ra, &sAh[nxt][0], &sAl[nxt][0]);
            cur = nxt;
        }
    }

    #pragma unroll
    for (int mi = 0; mi < 4; ++mi) {
        #pragma unroll
        for (int ni = 0; ni < 4; ++ni) {
            int c = n0 + wc * 64 + ni * 16 + lrow;
            float bv = bias[c];
            #pragma unroll
            for (int j = 0; j < 4; ++j) {
                int r = m0 + wr * 64 + mi * 16 + lslot * 4 + j;
                float v = acc1[mi][ni][j] + acc2[mi][ni][j] * (1.0f / 4096.0f) + bv;
                float xv = X[(size_t)r * D_DIM + c];
                out[(size_t)r * D_DIM + c] = (xv != 0.0f) ? v : 0.0f;
            }
        }
    }
}

// ---------------------------------------------------------------------------
// Fallback: full-scan row-sum -> inv.
// ---------------------------------------------------------------------------
__global__ void row_sum_inv_kernel(const float* __restrict__ out, float* __restrict__ inv)
{
    int gw = (blockIdx.x * 256 + threadIdx.x) >> 6;
    int l  = threadIdx.x & 63;
    const float4* row = reinterpret_cast<const float4*>(out) + (size_t)gw * (D_DIM / 4);
    float s = 0.f;
    #pragma unroll
    for (int j = 0; j < 8; ++j) {
        float4 v = row[j * 64 + l];
        s += (v.x + v.y) + (v.z + v.w);
    }
    #pragma unroll
    for (int off = 32; off > 0; off >>= 1) s += __shfl_down(s, off, 64);
    if (l == 0) inv[gw] = (s != 0.0f) ? (1.0f / s) : 0.0f;
}

// ---------------------------------------------------------------------------
// Fallback: out[n,k] *= inv[n]
// ---------------------------------------------------------------------------
__global__ void scale_kernel(float* __restrict__ out, const float* __restrict__ inv)
{
    const int total = N_ROWS * (D_DIM / 4);
    float4* o = reinterpret_cast<float4*>(out);
    for (int i = blockIdx.x * blockDim.x + threadIdx.x; i < total;
         i += gridDim.x * blockDim.x) {
        float s  = inv[i >> 9];
        float4 v = o[i];
        v.x *= s; v.y *= s; v.z *= s; v.w *= s;
        o[i] = v;
    }
}

extern "C" void kernel_launch(void* const* d_in, const int* in_sizes, int n_in,
                              void* d_out, int out_size, void* d_ws, size_t ws_size,
                              hipStream_t stream)
{
    const float* X  = (const float*)d_in[0];
    const float* A  = (const float*)d_in[1];
    const float* b  = (const float*)d_in[2];
    float* out = (float*)d_out;

    const size_t nX = (size_t)N_ROWS * D_DIM;        // 33.55M
    const size_t nA = (size_t)D_DIM * D_DIM;         // 4.19M
    const size_t part_bytes = (size_t)N_ROWS * 32 * sizeof(float);   // 2 MiB
    const size_t mask_bytes = nX / 8;                // 4.19 MB
    const size_t need = part_bytes + 2 * nX * 2 + 2 * nA * 2 + mask_bytes;

    if (ws_size >= need) {
        float*         part = (float*)d_ws;
        _Float16*      Xh   = (_Float16*)((char*)d_ws + part_bytes);
        _Float16*      Xl   = Xh + nX;
        _Float16*      Ah   = Xl + nX;
        _Float16*      Al   = Ah + nA;
        unsigned char* mb   = (unsigned char*)(Al + nA);

        const int nX8    = (int)(nX / 8);
        const int total8 = (int)((nX + nA) / 8);
        hipLaunchKernelGGL(split_all_kernel, dim3((total8 + 255) / 256), dim3(256), 0, stream,
                           (const float4*)X, (half4_t*)Xh, (half4_t*)Xl, mb,
                           (const float4*)A, (half4_t*)Ah, (half4_t*)Al,
                           nX8, total8);
        hipLaunchKernelGGL(gemm_presplit_kernel, dim3((N_ROWS / BM) * (D_DIM / BN)), dim3(256), 0, stream,
                           Xh, Xl, Ah, Al, mb, b, out, part);
        hipLaunchKernelGGL(scale_fused_kernel, dim3(N_ROWS / 8), dim3(256), 0, stream,
                           out, part);
    } else {
        float* inv = (float*)d_ws;
        hipLaunchKernelGGL(gemm_mask_kernel, dim3((N_ROWS / BM) * (D_DIM / BN)), dim3(256), 0, stream,
                           X, A, b, out);
        hipLaunchKernelGGL(row_sum_inv_kernel, dim3(N_ROWS / 4), dim3(256), 0, stream, out, inv);
        hipLaunchKernelGGL(scale_kernel, dim3(2048), dim3(256), 0, stream, out, inv);
    }
}

// Round 11
// 474.981 us; speedup vs baseline: 8.3670x; 8.3670x over previous
//
#include <hip/hip_runtime.h>

#define N_ROWS 16384
#define D_DIM  2048
#define BM 128
#define BN 128
#define BK 32
#define NKT (D_DIM / BK)   // 64 K-steps

typedef __attribute__((ext_vector_type(8)))  _Float16 half8;
typedef __attribute__((ext_vector_type(4)))  _Float16 half4_t;
typedef __attribute__((ext_vector_type(4)))  float floatx4;

typedef __attribute__((address_space(1))) const unsigned int as1_uint;
typedef __attribute__((address_space(3))) unsigned int as3_uint;

__device__ __forceinline__ void gload_lds16(const _Float16* g, _Float16* l) {
    __builtin_amdgcn_global_load_lds((as1_uint*)g, (as3_uint*)l, 16, 0, 0);
}

// ---------------------------------------------------------------------------
// Combined pre-pass: one dispatch splits BOTH X (with mask bits) and A.
//   hi = (half)x ; lo = (half)((x - hi) * 4096)
// ---------------------------------------------------------------------------
__global__ void split_all_kernel(const float4* __restrict__ Xs,
                                 half4_t* __restrict__ Xdh,
                                 half4_t* __restrict__ Xdl,
                                 unsigned char* __restrict__ mask,
                                 const float4* __restrict__ As,
                                 half4_t* __restrict__ Adh,
                                 half4_t* __restrict__ Adl,
                                 int nX8, int total8)
{
    int i = blockIdx.x * blockDim.x + threadIdx.x;
    if (i >= total8) return;

    const float4* src; half4_t* dh; half4_t* dl; int j; bool domask;
    if (i < nX8) { src = Xs; dh = Xdh; dl = Xdl; j = i;       domask = true;  }
    else         { src = As; dh = Adh; dl = Adl; j = i - nX8; domask = false; }

    float4 a = src[2 * j];
    float4 b = src[2 * j + 1];
    half4_t ha, la, hb, lb;
    ha[0] = (_Float16)a.x; ha[1] = (_Float16)a.y;
    ha[2] = (_Float16)a.z; ha[3] = (_Float16)a.w;
    la[0] = (_Float16)((a.x - (float)ha[0]) * 4096.0f);
    la[1] = (_Float16)((a.y - (float)ha[1]) * 4096.0f);
    la[2] = (_Float16)((a.z - (float)ha[2]) * 4096.0f);
    la[3] = (_Float16)((a.w - (float)ha[3]) * 4096.0f);
    hb[0] = (_Float16)b.x; hb[1] = (_Float16)b.y;
    hb[2] = (_Float16)b.z; hb[3] = (_Float16)b.w;
    lb[0] = (_Float16)((b.x - (float)hb[0]) * 4096.0f);
    lb[1] = (_Float16)((b.y - (float)hb[1]) * 4096.0f);
    lb[2] = (_Float16)((b.z - (float)hb[2]) * 4096.0f);
    lb[3] = (_Float16)((b.w - (float)hb[3]) * 4096.0f);
    dh[2 * j] = ha; dh[2 * j + 1] = hb;
    dl[2 * j] = la; dl[2 * j + 1] = lb;
    if (domask) {
        unsigned int m = 0;
        m |= (a.x != 0.0f) ? 0x01u : 0u;  m |= (a.y != 0.0f) ? 0x02u : 0u;
        m |= (a.z != 0.0f) ? 0x04u : 0u;  m |= (a.w != 0.0f) ? 0x08u : 0u;
        m |= (b.x != 0.0f) ? 0x10u : 0u;  m |= (b.y != 0.0f) ? 0x20u : 0u;
        m |= (b.z != 0.0f) ? 0x40u : 0u;  m |= (b.w != 0.0f) ? 0x80u : 0u;
        mask[j] = (unsigned char)m;
    }
}

// ---------------------------------------------------------------------------
// GEMM (16x16x32 f16 MFMA) on pre-split fp16 — EXACT round-3/7/9 hot loop
// (413 µs, MfmaUtil 46%, 0 bank conflicts, verified 3x):
//   dot = hi*hi + (hi*lo + lo*hi)/4096   [fp32-level accuracy]
// Double-buffered LDS (64 KiB), global_load_lds width-16, XOR slot swizzle,
// r_tile-fastest XCD swizzle, NO forced launch-bounds occupancy (2 blocks/CU
// is register-bound: 128 AGPR acc + ~116 VGPR = ~244 unified; round 10
// proved forcing 4 waves/EU spills the accumulator catastrophically).
// Epilogue: bias + mask bits + fused per-row partial sums.
// ---------------------------------------------------------------------------
__global__ __launch_bounds__(256, 2)
void gemm_presplit_kernel(const _Float16* __restrict__ Xh,
                          const _Float16* __restrict__ Xl,
                          const _Float16* __restrict__ Ah,
                          const _Float16* __restrict__ Al,
                          const unsigned char* __restrict__ maskbits,
                          const float* __restrict__ bias,
                          float* __restrict__ out,
                          float* __restrict__ partials)
{
    __shared__ __align__(16) _Float16 sXh[2][BM * BK];
    __shared__ __align__(16) _Float16 sXl[2][BM * BK];
    __shared__ __align__(16) _Float16 sAh[2][BN * BK];
    __shared__ __align__(16) _Float16 sAl[2][BN * BK];

    const int t   = threadIdx.x;
    const int bid = blockIdx.x;

    const int xcd    = bid & 7;
    const int local  = bid >> 3;          // 0..255
    const int r_tile = (xcd << 4) + (local & 15);
    const int c_tile = local >> 4;
    const int m0 = r_tile * BM;
    const int n0 = c_tile * BN;

    const int lane  = t & 63;
    const int w     = t >> 6;
    const int wr    = w >> 1;
    const int wc    = w & 1;
    const int lrow  = lane & 15;
    const int lslot = lane >> 4;

    floatx4 acc1[4][4], acc2[4][4];
    #pragma unroll
    for (int mi = 0; mi < 4; ++mi)
        #pragma unroll
        for (int ni = 0; ni < 4; ++ni)
            #pragma unroll
            for (int j = 0; j < 4; ++j) { acc1[mi][ni][j] = 0.f; acc2[mi][ni][j] = 0.f; }

    const _Float16* gsrc;
    _Float16* lb0; _Float16* lb1;
    if      (w == 0) { gsrc = Xh + (size_t)m0 * D_DIM; lb0 = &sXh[0][0]; lb1 = &sXh[1][0]; }
    else if (w == 1) { gsrc = Xl + (size_t)m0 * D_DIM; lb0 = &sXl[0][0]; lb1 = &sXl[1][0]; }
    else if (w == 2) { gsrc = Ah + (size_t)n0 * D_DIM; lb0 = &sAh[0][0]; lb1 = &sAh[1][0]; }
    else             { gsrc = Al + (size_t)n0 * D_DIM; lb0 = &sAl[0][0]; lb1 = &sAl[1][0]; }

    int off8[8];
    #pragma unroll
    for (int i = 0; i < 8; ++i) {
        int c = i * 64 + lane;            // linear 16B chunk index in LDS
        int row = c >> 2;                 // 4 chunks per row
        int sp  = c & 3;                  // stored slot
        int kslot = sp ^ ((row >> 1) & 3);
        off8[i] = row * D_DIM + kslot * 8;
    }

    auto issue = [&](int buf, int kt) {
        _Float16* lb = buf ? lb1 : lb0;
        const _Float16* gk = gsrc + kt * BK;
        #pragma unroll
        for (int i = 0; i < 8; ++i)
            gload_lds16(gk + off8[i], lb + i * 512);
    };

    issue(0, 0);

    int cur = 0;
    for (int kt = 0; kt < NKT; ++kt) {
        __syncthreads();                  // drains loads -> buf[cur] ready
        if (kt + 1 < NKT) issue(cur ^ 1, kt + 1);

        half8 bhf[4], blf[4];
        #pragma unroll
        for (int ni = 0; ni < 4; ++ni) {
            int row = wc * 64 + ni * 16 + lrow;
            int off = row * BK + ((lslot ^ ((row >> 1) & 3)) << 3);
            bhf[ni] = *reinterpret_cast<const half8*>(&sAh[cur][off]);
            blf[ni] = *reinterpret_cast<const half8*>(&sAl[cur][off]);
        }
        #pragma unroll
        for (int mi = 0; mi < 4; ++mi) {
            int row = wr * 64 + mi * 16 + lrow;
            int off = row * BK + ((lslot ^ ((row >> 1) & 3)) << 3);
            half8 ah = *reinterpret_cast<const half8*>(&sXh[cur][off]);
            half8 al = *reinterpret_cast<const half8*>(&sXl[cur][off]);
            #pragma unroll
            for (int ni = 0; ni < 4; ++ni) {
                acc1[mi][ni] = __builtin_amdgcn_mfma_f32_16x16x32_f16(ah, bhf[ni], acc1[mi][ni], 0, 0, 0);
                acc2[mi][ni] = __builtin_amdgcn_mfma_f32_16x16x32_f16(ah, blf[ni], acc2[mi][ni], 0, 0, 0);
                acc2[mi][ni] = __builtin_amdgcn_mfma_f32_16x16x32_f16(al, bhf[ni], acc2[mi][ni], 0, 0, 0);
            }
        }
        cur ^= 1;
    }

    // Epilogue: bias + mask (bit array), write masked y_pred, fused per-row
    // partial sums. C/D layout: col = lane&15, row = (lane>>4)*4 + j.
    #pragma unroll
    for (int mi = 0; mi < 4; ++mi) {
        float rs[4];
        #pragma unroll
        for (int j = 0; j < 4; ++j) rs[j] = 0.f;
        #pragma unroll
        for (int ni = 0; ni < 4; ++ni) {
            int c = n0 + wc * 64 + ni * 16 + lrow;
            float bv = bias[c];
            #pragma unroll
            for (int j = 0; j < 4; ++j) {
                int r = m0 + wr * 64 + mi * 16 + lslot * 4 + j;
                size_t idx = (size_t)r * D_DIM + c;
                float v = acc1[mi][ni][j] + acc2[mi][ni][j] * (1.0f / 4096.0f) + bv;
                unsigned int bit = (maskbits[idx >> 3] >> (c & 7)) & 1u;
                float mv = bit ? v : 0.0f;
                out[idx] = mv;
                rs[j] += mv;
            }
        }
        #pragma unroll
        for (int j = 0; j < 4; ++j) {
            float s = rs[j];
            s += __shfl_xor(s, 1, 64);
            s += __shfl_xor(s, 2, 64);
            s += __shfl_xor(s, 4, 64);
            s += __shfl_xor(s, 8, 64);
            if (lrow == 0) {
                int r = m0 + wr * 64 + mi * 16 + lslot * 4 + j;
                partials[(size_t)r * 32 + c_tile * 2 + wc] = s;
            }
        }
    }
}

// ---------------------------------------------------------------------------
// Fused: reduce 32 partials per row -> inv, then scale the row in-place.
// ---------------------------------------------------------------------------
__global__ void scale_fused_kernel(float* __restrict__ out,
                                   const float* __restrict__ partials)
{
    int r   = blockIdx.x * 8 + (threadIdx.x >> 5);
    int l32 = threadIdx.x & 31;
    float s = partials[(size_t)r * 32 + l32];
    s += __shfl_xor(s, 1, 32);
    s += __shfl_xor(s, 2, 32);
    s += __shfl_xor(s, 4, 32);
    s += __shfl_xor(s, 8, 32);
    s += __shfl_xor(s, 16, 32);
    float inv = (s != 0.0f) ? (1.0f / s) : 0.0f;
    float4* rowp = reinterpret_cast<float4*>(out + (size_t)r * D_DIM);
    #pragma unroll
    for (int j = 0; j < 16; ++j) {
        float4 v = rowp[j * 32 + l32];
        v.x *= inv; v.y *= inv; v.z *= inv; v.w *= inv;
        rowp[j * 32 + l32] = v;
    }
}

// ---------------------------------------------------------------------------
// Fallback GEMM (round-1 proven kernel) if ws_size is too small.
// ---------------------------------------------------------------------------
__global__ __launch_bounds__(256, 2)
void gemm_mask_kernel(const float* __restrict__ X,
                      const float* __restrict__ A,
                      const float* __restrict__ bias,
                      float* __restrict__ out)
{
    __shared__ __align__(16) _Float16 sXh[2][BM * BK];
    __shared__ __align__(16) _Float16 sXl[2][BM * BK];
    __shared__ __align__(16) _Float16 sAh[2][BN * BK];
    __shared__ __align__(16) _Float16 sAl[2][BN * BK];

    const int t   = threadIdx.x;
    const int bid = blockIdx.x;
    const int xcd    = bid & 7;
    const int local  = bid >> 3;
    const int r_tile = (xcd << 4) + (local & 15);
    const int c_tile = local >> 4;
    const int m0 = r_tile * BM;
    const int n0 = c_tile * BN;

    const int lane  = t & 63;
    const int w     = t >> 6;
    const int wr    = w >> 1;
    const int wc    = w & 1;
    const int lrow  = lane & 15;
    const int lslot = lane >> 4;

    const float4* X4 = reinterpret_cast<const float4*>(X);
    const float4* A4 = reinterpret_cast<const float4*>(A);

    floatx4 acc1[4][4], acc2[4][4];
    #pragma unroll
    for (int mi = 0; mi < 4; ++mi)
        #pragma unroll
        for (int ni = 0; ni < 4; ++ni)
            #pragma unroll
            for (int j = 0; j < 4; ++j) { acc1[mi][ni][j] = 0.f; acc2[mi][ni][j] = 0.f; }

    float4 rx[4], ra[4];
    #pragma unroll
    for (int i = 0; i < 4; ++i) {
        int f = i * 256 + t; int row = f >> 3; int k4 = f & 7;
        rx[i] = X4[(size_t)(m0 + row) * (D_DIM / 4) + k4];
        ra[i] = A4[(size_t)(n0 + row) * (D_DIM / 4) + k4];
    }

    auto stage = [&](const float4* rv, _Float16* dsh, _Float16* dsl) {
        #pragma unroll
        for (int i = 0; i < 4; ++i) {
            int f = i * 256 + t; int row = f >> 3; int k4 = f & 7;
            float4 v = rv[i];
            half4_t h, l;
            h[0] = (_Float16)v.x; h[1] = (_Float16)v.y;
            h[2] = (_Float16)v.z; h[3] = (_Float16)v.w;
            l[0] = (_Float16)((v.x - (float)h[0]) * 4096.0f);
            l[1] = (_Float16)((v.y - (float)h[1]) * 4096.0f);
            l[2] = (_Float16)((v.z - (float)h[2]) * 4096.0f);
            l[3] = (_Float16)((v.w - (float)h[3]) * 4096.0f);
            int off = row * BK + ((((k4 >> 1) ^ ((row >> 1) & 3)) << 3) + ((k4 & 1) << 2));
            *reinterpret_cast<half4_t*>(dsh + off) = h;
            *reinterpret_cast<half4_t*>(dsl + off) = l;
        }
    };

    stage(rx, &sXh[0][0], &sXl[0][0]);
    stage(ra, &sAh[0][0], &sAl[0][0]);

    int cur = 0;
    for (int kt = 0; kt < NKT; ++kt) {
        __syncthreads();
        const bool more = (kt + 1 < NKT);
        if (more) {
            int kb = (kt + 1) * (BK / 4);
            #pragma unroll
            for (int i = 0; i < 4; ++i) {
                int f = i * 256 + t; int row = f >> 3; int k4 = f & 7;
                rx[i] = X4[(size_t)(m0 + row) * (D_DIM / 4) + kb + k4];
                ra[i] = A4[(size_t)(n0 + row) * (D_DIM / 4) + kb + k4];
            }
        }

        half8 bhf[4], blf[4];
        #pragma unroll
        for (int ni = 0; ni < 4; ++ni) {
            int row = wc * 64 + ni * 16 + lrow;
            int off = row * BK + ((lslot ^ ((row >> 1) & 3)) << 3);
            bhf[ni] = *reinterpret_cast<const half8*>(&sAh[cur][off]);
            blf[ni] = *reinterpret_cast<const half8*>(&sAl[cur][off]);
        }
        #pragma unroll
        for (int mi = 0; mi < 4; ++mi) {
            int row = wr * 64 + mi * 16 + lrow;
            int off = row * BK + ((lslot ^ ((row >> 1) & 3)) << 3);
            half8 ah = *reinterpret_cast<const half8*>(&sXh[cur][off]);
            half8 al = *reinterpret_cast<const half8*>(&sXl[cur][off]);
            #pragma unroll
            for (int ni = 0; ni < 4; ++ni) {
                acc1[mi][ni] = __builtin_amdgcn_mfma_f32_16x16x32_f16(ah, bhf[ni], acc1[mi][ni], 0, 0, 0);
                acc2[mi][ni] = __builtin_amdgcn_mfma_f32_16x16x32_f16(ah, blf[ni], acc2[mi][ni], 0, 0, 0);
                acc2[mi][ni] = __builtin_amdgcn_mfma_f32_16x16x32_f16(al, bhf[ni], acc2[mi][ni], 0, 0, 0);
            }
        }

        if (more) {
            int nxt = cur ^ 1;
            stage(rx, &sXh[nxt][0], &sXl[nxt][0]);
            stage(ra, &sAh[nxt][0], &sAl[nxt][0]);
            cur = nxt;
        }
    }

    #pragma unroll
    for (int mi = 0; mi < 4; ++mi) {
        #pragma unroll
        for (int ni = 0; ni < 4; ++ni) {
            int c = n0 + wc * 64 + ni * 16 + lrow;
            float bv = bias[c];
            #pragma unroll
            for (int j = 0; j < 4; ++j) {
                int r = m0 + wr * 64 + mi * 16 + lslot * 4 + j;
                float v = acc1[mi][ni][j] + acc2[mi][ni][j] * (1.0f / 4096.0f) + bv;
                float xv = X[(size_t)r * D_DIM + c];
                out[(size_t)r * D_DIM + c] = (xv != 0.0f) ? v : 0.0f;
            }
        }
    }
}

// ---------------------------------------------------------------------------
// Fallback: full-scan row-sum -> inv.
// ---------------------------------------------------------------------------
__global__ void row_sum_inv_kernel(const float* __restrict__ out, float* __restrict__ inv)
{
    int gw = (blockIdx.x * 256 + threadIdx.x) >> 6;
    int l  = threadIdx.x & 63;
    const float4* row = reinterpret_cast<const float4*>(out) + (size_t)gw * (D_DIM / 4);
    float s = 0.f;
    #pragma unroll
    for (int j = 0; j < 8; ++j) {
        float4 v = row[j * 64 + l];
        s += (v.x + v.y) + (v.z + v.w);
    }
    #pragma unroll
    for (int off = 32; off > 0; off >>= 1) s += __shfl_down(s, off, 64);
    if (l == 0) inv[gw] = (s != 0.0f) ? (1.0f / s) : 0.0f;
}

// ---------------------------------------------------------------------------
// Fallback: out[n,k] *= inv[n]
// ---------------------------------------------------------------------------
__global__ void scale_kernel(float* __restrict__ out, const float* __restrict__ inv)
{
    const int total = N_ROWS * (D_DIM / 4);
    float4* o = reinterpret_cast<float4*>(out);
    for (int i = blockIdx.x * blockDim.x + threadIdx.x; i < total;
         i += gridDim.x * blockDim.x) {
        float s  = inv[i >> 9];
        float4 v = o[i];
        v.x *= s; v.y *= s; v.z *= s; v.w *= s;
        o[i] = v;
    }
}

extern "C" void kernel_launch(void* const* d_in, const int* in_sizes, int n_in,
                              void* d_out, int out_size, void* d_ws, size_t ws_size,
                              hipStream_t stream)
{
    const float* X  = (const float*)d_in[0];
    const float* A  = (const float*)d_in[1];
    const float* b  = (const float*)d_in[2];
    float* out = (float*)d_out;

    const size_t nX = (size_t)N_ROWS * D_DIM;        // 33.55M
    const size_t nA = (size_t)D_DIM * D_DIM;         // 4.19M
    const size_t part_bytes = (size_t)N_ROWS * 32 * sizeof(float);   // 2 MiB
    const size_t mask_bytes = nX / 8;                // 4.19 MB
    const size_t need = part_bytes + 2 * nX * 2 + 2 * nA * 2 + mask_bytes;

    if (ws_size >= need) {
        float*         part = (float*)d_ws;
        _Float16*      Xh   = (_Float16*)((char*)d_ws + part_bytes);
        _Float16*      Xl   = Xh + nX;
        _Float16*      Ah   = Xl + nX;
        _Float16*      Al   = Ah + nA;
        unsigned char* mb   = (unsigned char*)(Al + nA);

        const int nX8    = (int)(nX / 8);
        const int total8 = (int)((nX + nA) / 8);
        hipLaunchKernelGGL(split_all_kernel, dim3((total8 + 255) / 256), dim3(256), 0, stream,
                           (const float4*)X, (half4_t*)Xh, (half4_t*)Xl, mb,
                           (const float4*)A, (half4_t*)Ah, (half4_t*)Al,
                           nX8, total8);
        hipLaunchKernelGGL(gemm_presplit_kernel, dim3((N_ROWS / BM) * (D_DIM / BN)), dim3(256), 0, stream,
                           Xh, Xl, Ah, Al, mb, b, out, part);
        hipLaunchKernelGGL(scale_fused_kernel, dim3(N_ROWS / 8), dim3(256), 0, stream,
                           out, part);
    } else {
        float* inv = (float*)d_ws;
        hipLaunchKernelGGL(gemm_mask_kernel, dim3((N_ROWS / BM) * (D_DIM / BN)), dim3(256), 0, stream,
                           X, A, b, out);
        hipLaunchKernelGGL(row_sum_inv_kernel, dim3(N_ROWS / 4), dim3(256), 0, stream, out, inv);
        hipLaunchKernelGGL(scale_kernel, dim3(2048), dim3(256), 0, stream, out, inv);
    }
}